// Round 7
// baseline (757.006 us; speedup 1.0000x reference)
//
#include <hip/hip_runtime.h>
#include <hip/hip_bf16.h>
#include <math.h>

// Problem constants: N=100000, K=10, T=7, D=7, O=32
#define T_ 7
#define D_ 7
#define K_ 10
#define O_ 32
#define NREP 16           // replicated global accumulators
#define HROW 60           // padded LDS row floats (240B: 16B-aligned, banks coprime-ish)
#define NEG_SLOPE 0.01f

// ---------------- K0: zero the replicated output accumulators --------------
__global__ void k0_zero(float* __restrict__ acc) {
    int i = threadIdx.x;
    if (i < NREP * O_) acc[i] = 0.f;
}

// ---------------- fused kernel: 8 waves/block, wave w owns t=w -------------
// Block = 512 thr = 8 waves, 64 nodes. Waves 0..6: per-lane direct float2
// loads of xhet[t][node] (no LDS staging, no VGPR batching -> no spill bait;
// 280B lane stride puts ~64 lines in flight per instruction, L1 merges
// re-touches). Wave 7: self embedding. h exchanged via LDS, one barrier,
// distributed epilogue. launch_bounds(512,8) -> VGPR<=64 -> 32 waves/CU.
__global__ __launch_bounds__(512, 8) void k_fused(
    const float* __restrict__ xhet,   // [T,N,K,D]
    const float* __restrict__ xnode,  // [N,D]
    const int*   __restrict__ types,  // [N]
    const float* __restrict__ Wc,     // [T,D,D]
    const float* __restrict__ bc,     // [T,D]
    const float* __restrict__ Wagg,   // [O,56]
    const float* __restrict__ bagg,   // [O]
    float* __restrict__ acc_out,      // [NREP][O]
    int N)
{
    __shared__ __align__(16) float hbuf[64 * HROW];  // 15360 B
    __shared__ float sacc[O_];

    const int tx   = threadIdx.x;
    const int wv   = tx >> 6;
    const int lane = tx & 63;
    const int t    = __builtin_amdgcn_readfirstlane(wv);  // provably wave-uniform
    const int nodeBase = blockIdx.x * 64;
    const int n = nodeBase + lane;
    const bool active = (n < N);

    if (tx < O_) sacc[tx] = 0.f;

    if (t < T_) {
        // ---- neighbor-content wave for type t
        float w[D_][D_], bias[D_];                    // uniform t -> scalar loads
        #pragma unroll
        for (int o = 0; o < D_; ++o) {
            bias[o] = bc[t * D_ + o];
            #pragma unroll
            for (int d = 0; d < D_; ++d) w[o][d] = Wc[(t * D_ + o) * D_ + d];
        }

        float acc[D_] = {0.f, 0.f, 0.f, 0.f, 0.f, 0.f, 0.f};
        float cnt = 0.f;
        if (active) {
            const float2* p2 = (const float2*)(xhet + ((size_t)t * N + n) * 70);
            #pragma unroll
            for (int kk = 0; kk < K_ / 2; ++kk) {     // 5 pairs x 7 float2 (8B-aligned)
                float f[14];
                #pragma unroll
                for (int j = 0; j < 7; ++j) {
                    float2 v = p2[kk * 7 + j];        // one base + imm offsets
                    f[2 * j] = v.x; f[2 * j + 1] = v.y;
                }
                #pragma unroll
                for (int hh = 0; hh < 2; ++hh) {
                    float pre[D_];
                    #pragma unroll
                    for (int o = 0; o < D_; ++o) pre[o] = bias[o];
                    #pragma unroll
                    for (int d = 0; d < D_; ++d) {
                        const float xv = f[hh * 7 + d];
                        #pragma unroll
                        for (int o = 0; o < D_; ++o) pre[o] = fmaf(xv, w[o][d], pre[o]);
                    }
                    bool nz = false;
                    #pragma unroll
                    for (int o = 0; o < D_; ++o) nz = nz || (pre[o] != 0.f);
                    cnt += nz ? 1.f : 0.f;
                    #pragma unroll
                    for (int o = 0; o < D_; ++o)
                        acc[o] += (pre[o] >= 0.f) ? pre[o] : NEG_SLOPE * pre[o];
                }
            }
        }
        const float inv = 1.f / fmaxf(cnt, 1.f);
        #pragma unroll
        for (int o = 0; o < D_; ++o) hbuf[lane * HROW + t * D_ + o] = acc[o] * inv;
    } else {
        // ---- self-embedding wave: all 7 candidates (scalar weights), select by type
        float x[D_]; int tp = -1;
        if (active) {
            tp = types[n];
            #pragma unroll
            for (int d = 0; d < D_; ++d) x[d] = xnode[(size_t)n * D_ + d];
        } else {
            #pragma unroll
            for (int d = 0; d < D_; ++d) x[d] = 0.f;
        }
        float hs[D_] = {0.f, 0.f, 0.f, 0.f, 0.f, 0.f, 0.f};
        #pragma unroll
        for (int tt = 0; tt < T_; ++tt) {
            #pragma unroll
            for (int o = 0; o < D_; ++o) {
                float p = bc[tt * D_ + o];
                #pragma unroll
                for (int d = 0; d < D_; ++d) p = fmaf(x[d], Wc[(tt * D_ + o) * D_ + d], p);
                float c = (p >= 0.f) ? p : NEG_SLOPE * p;
                if (tp == tt) hs[o] = c;              // cndmask
            }
        }
        #pragma unroll
        for (int o = 0; o < D_; ++o) hbuf[lane * HROW + T_ * D_ + o] = hs[o];
    }

    __syncthreads();

    // ---- distributed epilogue: wave wv -> nodes wv*8..wv*8+7
    {
        const int node_sub = lane >> 3;               // 0..7
        const int node = wv * 8 + node_sub;           // 0..63
        const int og = lane & 7;                      // output group: o = og + 8j
        const bool act2 = (nodeBase + node) < N;

        const float4* h4 = (const float4*)(hbuf + node * HROW);  // 14 x b128, rows conflict-free
        float s0 = bagg[og], s1 = bagg[og + 8], s2 = bagg[og + 16], s3 = bagg[og + 24];
        const float4* w0 = (const float4*)(Wagg + (og)      * 56);  // 224B stride: 16B-aligned
        const float4* w1 = (const float4*)(Wagg + (og + 8)  * 56);
        const float4* w2 = (const float4*)(Wagg + (og + 16) * 56);
        const float4* w3 = (const float4*)(Wagg + (og + 24) * 56);
        #pragma unroll
        for (int q = 0; q < 14; ++q) {
            float4 hq = h4[q];                        // broadcast to 8 lanes of same node
            float4 a0 = w0[q], a1 = w1[q], a2 = w2[q], a3 = w3[q];  // L1-hot (7 KB)
            s0 += hq.x * a0.x + hq.y * a0.y + hq.z * a0.z + hq.w * a0.w;
            s1 += hq.x * a1.x + hq.y * a1.y + hq.z * a1.z + hq.w * a1.w;
            s2 += hq.x * a2.x + hq.y * a2.y + hq.z * a2.z + hq.w * a2.w;
            s3 += hq.x * a3.x + hq.y * a3.y + hq.z * a3.z + hq.w * a3.w;
        }
        float v0 = act2 ? 1.f / (1.f + __expf(-s0)) : 0.f;
        float v1 = act2 ? 1.f / (1.f + __expf(-s1)) : 0.f;
        float v2 = act2 ? 1.f / (1.f + __expf(-s2)) : 0.f;
        float v3 = act2 ? 1.f / (1.f + __expf(-s3)) : 0.f;
        #pragma unroll
        for (int m = 8; m < 64; m <<= 1) {            // reduce over node_sub bits
            v0 += __shfl_xor(v0, m);
            v1 += __shfl_xor(v1, m);
            v2 += __shfl_xor(v2, m);
            v3 += __shfl_xor(v3, m);
        }
        if (node_sub == 0) {
            atomicAdd(&sacc[og],      v0);
            atomicAdd(&sacc[og + 8],  v1);
            atomicAdd(&sacc[og + 16], v2);
            atomicAdd(&sacc[og + 24], v3);
        }
    }
    __syncthreads();
    if (tx < O_) atomicAdd(acc_out + (blockIdx.x & (NREP - 1)) * O_ + tx, sacc[tx]);
}

// ---------------- K3: sum replicas, divide by N into d_out -----------------
__global__ void k3_finish(const float* __restrict__ acc, float* __restrict__ out, float invN) {
    int o = threadIdx.x;
    if (o < O_) {
        float s = 0.f;
        #pragma unroll
        for (int rr = 0; rr < NREP; ++rr) s += acc[rr * O_ + o];
        out[o] = s * invN;
    }
}

extern "C" void kernel_launch(void* const* d_in, const int* in_sizes, int n_in,
                              void* d_out, int out_size, void* d_ws, size_t ws_size,
                              hipStream_t stream) {
    const float* xnode = (const float*)d_in[0];   // [N,D]
    const float* xhet  = (const float*)d_in[1];   // [T,N,K,D]
    const int*   types = (const int*)d_in[2];     // [N]
    const float* Wc    = (const float*)d_in[3];   // [T,D,D]
    const float* bc    = (const float*)d_in[4];   // [T,D]
    const float* Wagg  = (const float*)d_in[5];   // [O,56]
    const float* bagg  = (const float*)d_in[6];   // [O]
    float* out = (float*)d_out;

    const int N = in_sizes[2];
    float* acc_out = (float*)d_ws;                // NREP*32 floats

    const int nblk = (N + 63) / 64;

    k0_zero<<<1, 512, 0, stream>>>(acc_out);
    k_fused<<<nblk, 512, 0, stream>>>(xhet, xnode, types, Wc, bc, Wagg, bagg, acc_out, N);
    k3_finish<<<1, 64, 0, stream>>>(acc_out, out, 1.f / (float)N);
}